// Round 1
// baseline (435.287 us; speedup 1.0000x reference)
//
#include <hip/hip_runtime.h>

// LIF activation: Vm_{t+1} = relu(x_t + (1-w_leak)*Vm_t*[Vm_t<1]), spike = [Vm>1]
// [B,T,C] = [128,1000,512] fp32.
//
// R2 -> R3: 430us = ~1 HBM latency per timestep => effective MLP was ~1-2
// requests/wave and requests were only 256B (dword/lane) at 2KB stride.
// Restructure: each thread owns 4 adjacent channels -> every global access is
// a 1KB contiguous dwordx4 wave burst (matches the 6.4TB/s fill pattern), and
// U=20 float4 prefetch puts 20KB/wave in flight (need ~9KB/CU for 6.3TB/s at
// ~900cyc). Grid = 256 blocks x 64 threads = 1 wave per CU on all 256 CUs;
// 4 independent Vm chains/thread hide VALU dep latency.

constexpr int Bn  = 128;
constexpr int Tn  = 1000;
constexpr int Cn  = 512;
constexpr int C4  = Cn / 4;     // 128 float4 per (b,t) row
constexpr int U   = 20;         // timesteps per chunk
constexpr int NCH = Tn / U;     // 50 chunks (even -> clean 2x unroll)

// One LIF step for one channel; matches reference rounding exactly:
// separate mul, exact select for the keep-gate, add, relu, strict > for spike.
#define LIF_STEP(vm, oml, xin, sp)            \
    {                                          \
        float p_ = (oml) * (vm);               \
        p_ = ((vm) < 1.0f) ? p_ : 0.0f;        \
        float t_ = (xin) + p_;                 \
        (vm) = fmaxf(t_, 0.0f);                \
        (sp) = ((vm) > 1.0f) ? 1.0f : 0.0f;    \
    }

__global__ __launch_bounds__(64) void lif_kernel(const float4* __restrict__ x4,
                                                 const float*  __restrict__ w_leak,
                                                 float4* __restrict__ out4) {
    const int bid = blockIdx.x;                        // 0..255
    const int b   = bid >> 1;                          // 0..127
    const int c4  = ((bid & 1) << 6) | threadIdx.x;    // float4 column 0..127

    const float4 wl  = reinterpret_cast<const float4*>(w_leak)[c4];
    const float omlx = 1.0f - wl.x;
    const float omly = 1.0f - wl.y;
    const float omlz = 1.0f - wl.z;
    const float omlw = 1.0f - wl.w;

    const size_t base = (size_t)b * Tn * C4 + c4;
    const float4* xp = x4 + base;
    float4*       op = out4 + base;

    float vmx = 0.0f, vmy = 0.0f, vmz = 0.0f, vmw = 0.0f;
    float4 bufA[U], bufB[U];

    // prologue: prefetch chunk 0
#pragma unroll
    for (int i = 0; i < U; ++i) bufA[i] = xp[i * C4];
    __builtin_amdgcn_sched_barrier(0);

    for (int ch = 0; ch < NCH; ch += 2) {
        // prefetch chunk ch+1 -> bufB (overlaps compute of bufA)
        {
            const float4* xn = xp + (size_t)(ch + 1) * U * C4;
#pragma unroll
            for (int i = 0; i < U; ++i) bufB[i] = xn[i * C4];
        }
        __builtin_amdgcn_sched_barrier(0);
        // compute + store chunk ch from bufA
        {
            float4* on = op + (size_t)ch * U * C4;
#pragma unroll
            for (int i = 0; i < U; ++i) {
                float4 xv = bufA[i];
                float4 s;
                LIF_STEP(vmx, omlx, xv.x, s.x);
                LIF_STEP(vmy, omly, xv.y, s.y);
                LIF_STEP(vmz, omlz, xv.z, s.z);
                LIF_STEP(vmw, omlw, xv.w, s.w);
                on[i * C4] = s;
            }
        }
        __builtin_amdgcn_sched_barrier(0);
        // prefetch chunk ch+2 -> bufA
        if (ch + 2 < NCH) {
            const float4* xn = xp + (size_t)(ch + 2) * U * C4;
#pragma unroll
            for (int i = 0; i < U; ++i) bufA[i] = xn[i * C4];
        }
        __builtin_amdgcn_sched_barrier(0);
        // compute + store chunk ch+1 from bufB
        {
            float4* on = op + (size_t)(ch + 1) * U * C4;
#pragma unroll
            for (int i = 0; i < U; ++i) {
                float4 xv = bufB[i];
                float4 s;
                LIF_STEP(vmx, omlx, xv.x, s.x);
                LIF_STEP(vmy, omly, xv.y, s.y);
                LIF_STEP(vmz, omlz, xv.z, s.z);
                LIF_STEP(vmw, omlw, xv.w, s.w);
                on[i * C4] = s;
            }
        }
        __builtin_amdgcn_sched_barrier(0);
    }
}

extern "C" void kernel_launch(void* const* d_in, const int* in_sizes, int n_in,
                              void* d_out, int out_size, void* d_ws, size_t ws_size,
                              hipStream_t stream) {
    const float4* x      = (const float4*)d_in[0];
    const float*  w_leak = (const float*)d_in[1];
    float4*       out    = (float4*)d_out;

    // 256 blocks x 64 threads: one wave per block, one block per CU.
    // Each block covers (b = bid>>1, half of the C dimension).
    lif_kernel<<<256, 64, 0, stream>>>(x, w_leak, out);
}